// Round 4
// baseline (664.706 us; speedup 1.0000x reference)
//
#include <hip/hip_runtime.h>
#include <hip/hip_bf16.h>
#include <stdint.h>

#define DIM 2048
#define HID 5632

typedef __attribute__((ext_vector_type(8))) short short8;
typedef __attribute__((ext_vector_type(4))) float f32x4;
typedef __attribute__((ext_vector_type(4))) int int4v;
typedef __attribute__((ext_vector_type(4))) unsigned short ushort4v;

__device__ __forceinline__ unsigned short f32_to_bf16_rne(float f) {
    union { float f; unsigned u; } v; v.f = f;
    unsigned u = v.u;
    return (unsigned short)((u + 0x7FFFu + ((u >> 16) & 1u)) >> 16);
}

__device__ __forceinline__ void gload16(const void* g, void* l) {
    __builtin_amdgcn_global_load_lds(
        (const __attribute__((address_space(1))) void*)g,
        (__attribute__((address_space(3))) void*)l,
        16, 0, 0);
}

// phase boilerplate: barrier -> drain LDS reads -> MFMA cluster -> barrier
#define PHASE_BEGIN \
    __builtin_amdgcn_sched_barrier(0); \
    __builtin_amdgcn_s_barrier(); \
    asm volatile("s_waitcnt lgkmcnt(0)" ::: "memory"); \
    __builtin_amdgcn_sched_barrier(0); \
    __builtin_amdgcn_s_setprio(1);
#define PHASE_END \
    __builtin_amdgcn_s_setprio(0); \
    __builtin_amdgcn_sched_barrier(0); \
    __builtin_amdgcn_s_barrier(); \
    __builtin_amdgcn_sched_barrier(0);

// ---- dequant down weights (plain row-major) ----
__global__ void dequant_plain(const int* __restrict__ wq, const float* __restrict__ scale,
                              unsigned short* __restrict__ out, long total, int cols) {
    long n4 = total >> 2;
    long stride = (long)gridDim.x * blockDim.x;
    for (long i = (long)blockIdx.x * blockDim.x + threadIdx.x; i < n4; i += stride) {
        int4v c = ((const int4v*)wq)[i];
        int row = (int)((i << 2) / cols);
        float s = scale[row];
        ushort4v o;
        o.x = f32_to_bf16_rne(((float)c.x - 128.0f) * s);
        o.y = f32_to_bf16_rne(((float)c.y - 128.0f) * s);
        o.z = f32_to_bf16_rne(((float)c.z - 128.0f) * s);
        o.w = f32_to_bf16_rne(((float)c.w - 128.0f) * s);
        ((ushort4v*)out)[i] = o;
    }
}

// ---- dequant gate+up into 16-row-interleaved W' [2*HID][DIM] ----
__global__ void dequant_gateup(const int* __restrict__ wg, const float* __restrict__ sg,
                               const int* __restrict__ wu, const float* __restrict__ su,
                               unsigned short* __restrict__ out) {
    const long n4 = (long)HID * DIM / 4;
    long stride = (long)gridDim.x * blockDim.x;
    for (long i = (long)blockIdx.x * blockDim.x + threadIdx.x; i < n4; i += stride) {
        int r  = (int)(i >> 9);
        int c4 = (int)(i & 511);
        int rp = ((r >> 4) << 5) + (r & 15);
        float s1 = sg[r], s2 = su[r];
        int4v g = ((const int4v*)wg)[i];
        int4v u = ((const int4v*)wu)[i];
        ushort4v og, ou;
        og.x = f32_to_bf16_rne(((float)g.x - 128.0f) * s1);
        og.y = f32_to_bf16_rne(((float)g.y - 128.0f) * s1);
        og.z = f32_to_bf16_rne(((float)g.z - 128.0f) * s1);
        og.w = f32_to_bf16_rne(((float)g.w - 128.0f) * s1);
        ou.x = f32_to_bf16_rne(((float)u.x - 128.0f) * s2);
        ou.y = f32_to_bf16_rne(((float)u.y - 128.0f) * s2);
        ou.z = f32_to_bf16_rne(((float)u.z - 128.0f) * s2);
        ou.w = f32_to_bf16_rne(((float)u.w - 128.0f) * s2);
        ((ushort4v*)out)[(long)rp * 512 + c4]        = og;
        ((ushort4v*)out)[(long)(rp + 16) * 512 + c4] = ou;
    }
}

// ---- x: f32 -> bf16 ----
__global__ void cast_f32_bf16(const float* __restrict__ in, unsigned short* __restrict__ out, long n) {
    long n4 = n >> 2;
    long stride = (long)gridDim.x * blockDim.x;
    for (long i = (long)blockIdx.x * blockDim.x + threadIdx.x; i < n4; i += stride) {
        f32x4 v = ((const f32x4*)in)[i];
        ushort4v o;
        o.x = f32_to_bf16_rne(v[0]);
        o.y = f32_to_bf16_rne(v[1]);
        o.z = f32_to_bf16_rne(v[2]);
        o.w = f32_to_bf16_rne(v[3]);
        ((ushort4v*)out)[i] = o;
    }
}

// =====================================================================
// 256x256 BK=64, double-buffered LDS with XOR swizzle, 4-phase-per-K-tile
// schedule (T2+T3+T4+T5). 512 threads = 8 waves (2Mx4N), wave tile 128x64.
// =====================================================================

// ---- fused gate+up: H[M][HID] bf16 = silu(X@Wg^T)*(X@Wu^T), W' interleaved ----
__global__ __launch_bounds__(512, 2) void gemm_gateup(
    const unsigned short* __restrict__ X,
    const unsigned short* __restrict__ Wp,
    unsigned short* __restrict__ H)
{
    __shared__ __attribute__((aligned(16))) unsigned short As[2][256 * 64];
    __shared__ __attribute__((aligned(16))) unsigned short Bs[2][256 * 64];

    const int tid  = threadIdx.x;
    const int lane = tid & 63;
    const int wid  = tid >> 6;
    const int wr   = wid >> 2;
    const int wc   = wid & 3;
    const int m0   = blockIdx.x << 8;
    const int n0   = blockIdx.y << 8;
    const int lr   = lane & 15;
    const int kg   = lane >> 4;

    int srow[4], skc[4], sdst[4];
    #pragma unroll
    for (int l = 0; l < 4; ++l) {
        int q = l * 512 + tid;
        srow[l] = q >> 3;
        skc[l]  = (((q & 7) ^ ((q >> 3) & 7)) << 3);
        sdst[l] = q << 3;
    }

    auto STAGE = [&](int buf, int kt) {
        const int kk = kt << 6;
        #pragma unroll
        for (int l = 0; l < 4; ++l) {
            gload16(X  + (size_t)(m0 + srow[l]) * DIM + kk + skc[l], &As[buf][sdst[l]]);
            gload16(Wp + (size_t)(n0 + srow[l]) * DIM + kk + skc[l], &Bs[buf][sdst[l]]);
        }
    };

    f32x4 acc[8][4];
    #pragma unroll
    for (int m = 0; m < 8; ++m)
        #pragma unroll
        for (int n = 0; n < 4; ++n) acc[m][n] = (f32x4){0.f, 0.f, 0.f, 0.f};

    const int c0 = ((kg ^ (lr & 7)) << 3);
    const int c1 = (((4 + kg) ^ (lr & 7)) << 3);
    const int abase = (wr * 128 + lr) * 64;
    const int bbase = (wc * 64 + lr) * 64;

    STAGE(0, 0);
    STAGE(1, 1);

    const int NT = DIM / 64;  // 32
    for (int kt = 0; kt < NT; ++kt) {
        const int cur = kt & 1;
        if (kt < NT - 1) asm volatile("s_waitcnt vmcnt(8)" ::: "memory");
        else             asm volatile("s_waitcnt vmcnt(0)" ::: "memory");
        __builtin_amdgcn_sched_barrier(0);
        __builtin_amdgcn_s_barrier();
        __builtin_amdgcn_sched_barrier(0);

        const unsigned short* ap0 = &As[cur][abase + c0];
        const unsigned short* ap1 = &As[cur][abase + c1];
        const unsigned short* bp0 = &Bs[cur][bbase + c0];
        const unsigned short* bp1 = &Bs[cur][bbase + c1];

        // P0: B[k0] + A[m0..3][k0]
        short8 b0[4], a0[4];
        #pragma unroll
        for (int n = 0; n < 4; ++n) b0[n] = *(const short8*)(bp0 + (n << 10));
        #pragma unroll
        for (int m = 0; m < 4; ++m) a0[m] = *(const short8*)(ap0 + (m << 10));
        PHASE_BEGIN
        #pragma unroll
        for (int m = 0; m < 4; ++m)
            #pragma unroll
            for (int n = 0; n < 4; ++n)
                acc[m][n] = __builtin_amdgcn_mfma_f32_16x16x32_bf16(a0[m], b0[n], acc[m][n], 0, 0, 0);
        PHASE_END

        // P1: A[m4..7][k0]
        short8 a1[4];
        #pragma unroll
        for (int m = 0; m < 4; ++m) a1[m] = *(const short8*)(ap0 + ((m + 4) << 10));
        PHASE_BEGIN
        #pragma unroll
        for (int m = 0; m < 4; ++m)
            #pragma unroll
            for (int n = 0; n < 4; ++n)
                acc[m + 4][n] = __builtin_amdgcn_mfma_f32_16x16x32_bf16(a1[m], b0[n], acc[m + 4][n], 0, 0, 0);
        PHASE_END

        // P2: B[k1] + A[m0..3][k1]
        short8 b1[4], a2[4];
        #pragma unroll
        for (int n = 0; n < 4; ++n) b1[n] = *(const short8*)(bp1 + (n << 10));
        #pragma unroll
        for (int m = 0; m < 4; ++m) a2[m] = *(const short8*)(ap1 + (m << 10));
        PHASE_BEGIN
        #pragma unroll
        for (int m = 0; m < 4; ++m)
            #pragma unroll
            for (int n = 0; n < 4; ++n)
                acc[m][n] = __builtin_amdgcn_mfma_f32_16x16x32_bf16(a2[m], b1[n], acc[m][n], 0, 0, 0);
        PHASE_END

        // P3: A[m4..7][k1]
        short8 a3[4];
        #pragma unroll
        for (int m = 0; m < 4; ++m) a3[m] = *(const short8*)(ap1 + ((m + 4) << 10));
        PHASE_BEGIN
        #pragma unroll
        for (int m = 0; m < 4; ++m)
            #pragma unroll
            for (int n = 0; n < 4; ++n)
                acc[m + 4][n] = __builtin_amdgcn_mfma_f32_16x16x32_bf16(a3[m], b1[n], acc[m + 4][n], 0, 0, 0);
        PHASE_END

        if (kt + 2 < NT) STAGE(cur, kt + 2);
        __builtin_amdgcn_sched_barrier(0);
    }

    // epilogue: n even = gate frag, n odd = up frag (same H columns)
    const int lg = lane >> 4;
    #pragma unroll
    for (int m = 0; m < 8; ++m) {
        #pragma unroll
        for (int i = 0; i < 2; ++i) {
            f32x4 g = acc[m][2 * i], u = acc[m][2 * i + 1];
            const int col = (blockIdx.y << 7) + wc * 32 + i * 16 + lr;
            #pragma unroll
            for (int e = 0; e < 4; ++e) {
                const int row = m0 + wr * 128 + m * 16 + lg * 4 + e;
                float gv = g[e];
                float sg = gv / (1.0f + __expf(-gv));
                H[(size_t)row * HID + col] = f32_to_bf16_rne(sg * u[e]);
            }
        }
    }
}

// ---- down: Out[M][DIM] f32 = H @ Wd^T ----
__global__ __launch_bounds__(512, 2) void gemm_down(
    const unsigned short* __restrict__ Hb,
    const unsigned short* __restrict__ Wd,
    float* __restrict__ Out)
{
    __shared__ __attribute__((aligned(16))) unsigned short As[2][256 * 64];
    __shared__ __attribute__((aligned(16))) unsigned short Bs[2][256 * 64];

    const int tid  = threadIdx.x;
    const int lane = tid & 63;
    const int wid  = tid >> 6;
    const int wr   = wid >> 2;
    const int wc   = wid & 3;
    const int m0   = blockIdx.x << 8;
    const int n0   = blockIdx.y << 8;
    const int lr   = lane & 15;
    const int kg   = lane >> 4;

    int srow[4], skc[4], sdst[4];
    #pragma unroll
    for (int l = 0; l < 4; ++l) {
        int q = l * 512 + tid;
        srow[l] = q >> 3;
        skc[l]  = (((q & 7) ^ ((q >> 3) & 7)) << 3);
        sdst[l] = q << 3;
    }

    auto STAGE = [&](int buf, int kt) {
        const int kk = kt << 6;
        #pragma unroll
        for (int l = 0; l < 4; ++l) {
            gload16(Hb + (size_t)(m0 + srow[l]) * HID + kk + skc[l], &As[buf][sdst[l]]);
            gload16(Wd + (size_t)(n0 + srow[l]) * HID + kk + skc[l], &Bs[buf][sdst[l]]);
        }
    };

    f32x4 acc[8][4];
    #pragma unroll
    for (int m = 0; m < 8; ++m)
        #pragma unroll
        for (int n = 0; n < 4; ++n) acc[m][n] = (f32x4){0.f, 0.f, 0.f, 0.f};

    const int c0 = ((kg ^ (lr & 7)) << 3);
    const int c1 = (((4 + kg) ^ (lr & 7)) << 3);
    const int abase = (wr * 128 + lr) * 64;
    const int bbase = (wc * 64 + lr) * 64;

    STAGE(0, 0);
    STAGE(1, 1);

    const int NT = HID / 64;  // 88
    for (int kt = 0; kt < NT; ++kt) {
        const int cur = kt & 1;
        if (kt < NT - 1) asm volatile("s_waitcnt vmcnt(8)" ::: "memory");
        else             asm volatile("s_waitcnt vmcnt(0)" ::: "memory");
        __builtin_amdgcn_sched_barrier(0);
        __builtin_amdgcn_s_barrier();
        __builtin_amdgcn_sched_barrier(0);

        const unsigned short* ap0 = &As[cur][abase + c0];
        const unsigned short* ap1 = &As[cur][abase + c1];
        const unsigned short* bp0 = &Bs[cur][bbase + c0];
        const unsigned short* bp1 = &Bs[cur][bbase + c1];

        short8 b0[4], a0[4];
        #pragma unroll
        for (int n = 0; n < 4; ++n) b0[n] = *(const short8*)(bp0 + (n << 10));
        #pragma unroll
        for (int m = 0; m < 4; ++m) a0[m] = *(const short8*)(ap0 + (m << 10));
        PHASE_BEGIN
        #pragma unroll
        for (int m = 0; m < 4; ++m)
            #pragma unroll
            for (int n = 0; n < 4; ++n)
                acc[m][n] = __builtin_amdgcn_mfma_f32_16x16x32_bf16(a0[m], b0[n], acc[m][n], 0, 0, 0);
        PHASE_END

        short8 a1[4];
        #pragma unroll
        for (int m = 0; m < 4; ++m) a1[m] = *(const short8*)(ap0 + ((m + 4) << 10));
        PHASE_BEGIN
        #pragma unroll
        for (int m = 0; m < 4; ++m)
            #pragma unroll
            for (int n = 0; n < 4; ++n)
                acc[m + 4][n] = __builtin_amdgcn_mfma_f32_16x16x32_bf16(a1[m], b0[n], acc[m + 4][n], 0, 0, 0);
        PHASE_END

        short8 b1[4], a2[4];
        #pragma unroll
        for (int n = 0; n < 4; ++n) b1[n] = *(const short8*)(bp1 + (n << 10));
        #pragma unroll
        for (int m = 0; m < 4; ++m) a2[m] = *(const short8*)(ap1 + (m << 10));
        PHASE_BEGIN
        #pragma unroll
        for (int m = 0; m < 4; ++m)
            #pragma unroll
            for (int n = 0; n < 4; ++n)
                acc[m][n] = __builtin_amdgcn_mfma_f32_16x16x32_bf16(a2[m], b1[n], acc[m][n], 0, 0, 0);
        PHASE_END

        short8 a3[4];
        #pragma unroll
        for (int m = 0; m < 4; ++m) a3[m] = *(const short8*)(ap1 + ((m + 4) << 10));
        PHASE_BEGIN
        #pragma unroll
        for (int m = 0; m < 4; ++m)
            #pragma unroll
            for (int n = 0; n < 4; ++n)
                acc[m + 4][n] = __builtin_amdgcn_mfma_f32_16x16x32_bf16(a3[m], b1[n], acc[m + 4][n], 0, 0, 0);
        PHASE_END

        if (kt + 2 < NT) STAGE(cur, kt + 2);
        __builtin_amdgcn_sched_barrier(0);
    }

    const int lg = lane >> 4;
    #pragma unroll
    for (int m = 0; m < 8; ++m) {
        #pragma unroll
        for (int n = 0; n < 4; ++n) {
            const int col = n0 + wc * 64 + n * 16 + lr;
            #pragma unroll
            for (int e = 0; e < 4; ++e) {
                const int row = m0 + wr * 128 + m * 16 + lg * 4 + e;
                Out[(size_t)row * DIM + col] = acc[m][n][e];
            }
        }
    }
}

extern "C" void kernel_launch(void* const* d_in, const int* in_sizes, int n_in,
                              void* d_out, int out_size, void* d_ws, size_t ws_size,
                              hipStream_t stream) {
    const float* x      = (const float*)d_in[0];
    const int* wq_gate  = (const int*)d_in[1];
    const float* s_gate = (const float*)d_in[2];
    const int* wq_up    = (const int*)d_in[3];
    const float* s_up   = (const float*)d_in[4];
    const int* wq_down  = (const int*)d_in[5];
    const float* s_down = (const float*)d_in[6];
    float* out = (float*)d_out;

    const int M = in_sizes[0] / DIM;  // 8192

    // ws layout (elems, bf16): xb [M*DIM] | wgu [2*HID*DIM] (down weights alias) | h [M*HID]
    unsigned short* xb  = (unsigned short*)d_ws;
    unsigned short* wgu = xb + (size_t)M * DIM;
    unsigned short* h   = wgu + (size_t)2 * HID * DIM;

    cast_f32_bf16<<<2048, 256, 0, stream>>>(x, xb, (long)M * DIM);
    dequant_gateup<<<2048, 256, 0, stream>>>(wq_gate, s_gate, wq_up, s_up, wgu);

    gemm_gateup<<<dim3(M / 256, (2 * HID) / 256), 512, 0, stream>>>(xb, wgu, h);

    dequant_plain<<<2048, 256, 0, stream>>>(wq_down, s_down, wgu, (long)DIM * HID, HID);

    gemm_down<<<dim3(M / 256, DIM / 256), 512, 0, stream>>>(h, wgu, out);
}

// Round 6
// 597.790 us; speedup vs baseline: 1.1119x; 1.1119x over previous
//
#include <hip/hip_runtime.h>
#include <hip/hip_bf16.h>
#include <stdint.h>

#define DIM 2048
#define HID 5632

typedef __attribute__((ext_vector_type(8))) short short8;
typedef __attribute__((ext_vector_type(4))) float f32x4;
typedef __attribute__((ext_vector_type(4))) int int4v;
typedef __attribute__((ext_vector_type(4))) unsigned short ushort4v;

__device__ __forceinline__ unsigned short f32_to_bf16_rne(float f) {
    union { float f; unsigned u; } v; v.f = f;
    unsigned u = v.u;
    return (unsigned short)((u + 0x7FFFu + ((u >> 16) & 1u)) >> 16);
}

__device__ __forceinline__ void gload16(const void* g, void* l) {
    __builtin_amdgcn_global_load_lds(
        (const __attribute__((address_space(1))) void*)g,
        (__attribute__((address_space(3))) void*)l,
        16, 0, 0);
}

// phase open: barrier -> drain LDS reads -> MFMA cluster
#define PH_OPEN \
    __builtin_amdgcn_sched_barrier(0); \
    __builtin_amdgcn_s_barrier(); \
    asm volatile("s_waitcnt lgkmcnt(0)" ::: "memory"); \
    __builtin_amdgcn_sched_barrier(0); \
    __builtin_amdgcn_s_setprio(1);
#define PH_CLOSE \
    __builtin_amdgcn_s_setprio(0); \
    __builtin_amdgcn_sched_barrier(0); \
    __builtin_amdgcn_s_barrier(); \
    __builtin_amdgcn_sched_barrier(0);
// close with counted vmem wait BEFORE the barrier (gates next phase's ds_reads)
#define PH_CLOSE_VM(N) \
    __builtin_amdgcn_s_setprio(0); \
    __builtin_amdgcn_sched_barrier(0); \
    asm volatile("s_waitcnt vmcnt(" #N ")" ::: "memory"); \
    __builtin_amdgcn_sched_barrier(0); \
    __builtin_amdgcn_s_barrier(); \
    __builtin_amdgcn_sched_barrier(0);

// ---- dequant down weights (plain row-major) ----
__global__ void dequant_plain(const int* __restrict__ wq, const float* __restrict__ scale,
                              unsigned short* __restrict__ out, long total, int cols) {
    long n4 = total >> 2;
    long stride = (long)gridDim.x * blockDim.x;
    for (long i = (long)blockIdx.x * blockDim.x + threadIdx.x; i < n4; i += stride) {
        int4v c = ((const int4v*)wq)[i];
        int row = (int)((i << 2) / cols);
        float s = scale[row];
        ushort4v o;
        o.x = f32_to_bf16_rne(((float)c.x - 128.0f) * s);
        o.y = f32_to_bf16_rne(((float)c.y - 128.0f) * s);
        o.z = f32_to_bf16_rne(((float)c.z - 128.0f) * s);
        o.w = f32_to_bf16_rne(((float)c.w - 128.0f) * s);
        ((ushort4v*)out)[i] = o;
    }
}

// ---- dequant gate+up into 16-row-interleaved W' [2*HID][DIM] ----
__global__ void dequant_gateup(const int* __restrict__ wg, const float* __restrict__ sg,
                               const int* __restrict__ wu, const float* __restrict__ su,
                               unsigned short* __restrict__ out) {
    const long n4 = (long)HID * DIM / 4;
    long stride = (long)gridDim.x * blockDim.x;
    for (long i = (long)blockIdx.x * blockDim.x + threadIdx.x; i < n4; i += stride) {
        int r  = (int)(i >> 9);
        int c4 = (int)(i & 511);
        int rp = ((r >> 4) << 5) + (r & 15);
        float s1 = sg[r], s2 = su[r];
        int4v g = ((const int4v*)wg)[i];
        int4v u = ((const int4v*)wu)[i];
        ushort4v og, ou;
        og.x = f32_to_bf16_rne(((float)g.x - 128.0f) * s1);
        og.y = f32_to_bf16_rne(((float)g.y - 128.0f) * s1);
        og.z = f32_to_bf16_rne(((float)g.z - 128.0f) * s1);
        og.w = f32_to_bf16_rne(((float)g.w - 128.0f) * s1);
        ou.x = f32_to_bf16_rne(((float)u.x - 128.0f) * s2);
        ou.y = f32_to_bf16_rne(((float)u.y - 128.0f) * s2);
        ou.z = f32_to_bf16_rne(((float)u.z - 128.0f) * s2);
        ou.w = f32_to_bf16_rne(((float)u.w - 128.0f) * s2);
        ((ushort4v*)out)[(long)rp * 512 + c4]        = og;
        ((ushort4v*)out)[(long)(rp + 16) * 512 + c4] = ou;
    }
}

// ---- x: f32 -> bf16 ----
__global__ void cast_f32_bf16(const float* __restrict__ in, unsigned short* __restrict__ out, long n) {
    long n4 = n >> 2;
    long stride = (long)gridDim.x * blockDim.x;
    for (long i = (long)blockIdx.x * blockDim.x + threadIdx.x; i < n4; i += stride) {
        f32x4 v = ((const f32x4*)in)[i];
        ushort4v o;
        o.x = f32_to_bf16_rne(v[0]);
        o.y = f32_to_bf16_rne(v[1]);
        o.z = f32_to_bf16_rne(v[2]);
        o.w = f32_to_bf16_rne(v[3]);
        ((ushort4v*)out)[i] = o;
    }
}

// =====================================================================
// 256x256 BK=64, 4-phase/K-tile with PER-PHASE half-tile staging and
// counted vmcnt (m201 mechanism). LDS split [buf][khalf][256][32];
// swizzle: 16B-chunk ^= (row>>1)&3 within each half (2-way = free).
// Stage stream: t.Q1->A-k1(t+1), t.Q2->B-k1(t+1), t.Q3->A-k0(t+2),
// t.Q4->B-k0(t+2). vmcnt(8) before closing barriers of Q2 and Q4.
// 512 threads = 8 waves (2Mx4N), wave tile 128x64.
// =====================================================================

#define GEMM_PROLOGUE_COMMON(Aptr, Bptr, LDA, LDB)                                   \
    const int tid  = threadIdx.x;                                                    \
    const int lane = tid & 63;                                                       \
    const int wid  = tid >> 6;                                                       \
    const int wr   = wid >> 2;                                                       \
    const int wc   = wid & 3;                                                        \
    const int m0   = blockIdx.x << 8;                                                \
    const int n0   = blockIdx.y << 8;                                                \
    const int lr   = lane & 15;                                                      \
    const int kg   = lane >> 4;                                                      \
    const int ck   = ((kg ^ ((lr >> 1) & 3)) << 3);                                  \
    const int aboff = (wr * 128 + lr) * 32;                                          \
    const int bboff = (wc * 64 + lr) * 32;                                           \
    int srow[2], scol[2], sdst[2];                                                   \
    _Pragma("unroll")                                                                \
    for (int l = 0; l < 2; ++l) {                                                    \
        int p = tid + (l << 9);                                                      \
        srow[l] = p >> 2;                                                            \
        scol[l] = (((p & 3) ^ ((p >> 3) & 3)) << 3);                                 \
        sdst[l] = p << 3;                                                            \
    }                                                                                \
    auto STAGE_A = [&](int t, int kh) {                                              \
        if (t < NT) {                                                                \
            unsigned short* dst = As + ((((t & 1) << 1) | kh) << 13);                \
            _Pragma("unroll")                                                        \
            for (int l = 0; l < 2; ++l)                                              \
                gload16(Aptr + (size_t)(m0 + srow[l]) * LDA + (t << 6) + (kh << 5) + scol[l], \
                        dst + sdst[l]);                                              \
        }                                                                            \
    };                                                                               \
    auto STAGE_B = [&](int t, int kh) {                                              \
        if (t < NT) {                                                                \
            unsigned short* dst = Bs + ((((t & 1) << 1) | kh) << 13);                \
            _Pragma("unroll")                                                        \
            for (int l = 0; l < 2; ++l)                                              \
                gload16(Bptr + (size_t)(n0 + srow[l]) * LDB + (t << 6) + (kh << 5) + scol[l], \
                        dst + sdst[l]);                                              \
        }                                                                            \
    };                                                                               \
    f32x4 acc[8][4];                                                                 \
    _Pragma("unroll")                                                                \
    for (int m = 0; m < 8; ++m)                                                      \
        _Pragma("unroll")                                                            \
        for (int n = 0; n < 4; ++n) acc[m][n] = (f32x4){0.f, 0.f, 0.f, 0.f};         \
    /* prologue: k0(0), k1(0), k0(1); confirm k0(0) landed */                        \
    STAGE_A(0, 0); STAGE_B(0, 0);                                                    \
    STAGE_A(0, 1); STAGE_B(0, 1);                                                    \
    STAGE_A(1, 0); STAGE_B(1, 0);                                                    \
    asm volatile("s_waitcnt vmcnt(8)" ::: "memory");                                 \
    __builtin_amdgcn_s_barrier();

#define GEMM_KLOOP_BODY                                                              \
    for (int t = 0; t < NT; ++t) {                                                   \
        const int buf = t & 1;                                                       \
        const unsigned short* a0p = As + ((buf << 1) << 13) + aboff + ck;            \
        const unsigned short* a1p = As + (((buf << 1) | 1) << 13) + aboff + ck;      \
        const unsigned short* b0p = Bs + ((buf << 1) << 13) + bboff + ck;            \
        const unsigned short* b1p = Bs + (((buf << 1) | 1) << 13) + bboff + ck;      \
        /* Q1: b0 + aL0 reads; stage A-k1(t+1) */                                    \
        short8 b0[4], aL0[4];                                                        \
        _Pragma("unroll")                                                            \
        for (int n = 0; n < 4; ++n) b0[n] = *(const short8*)(b0p + (n << 9));        \
        _Pragma("unroll")                                                            \
        for (int m = 0; m < 4; ++m) aL0[m] = *(const short8*)(a0p + (m << 9));       \
        STAGE_A(t + 1, 1);                                                           \
        PH_OPEN                                                                      \
        _Pragma("unroll")                                                            \
        for (int m = 0; m < 4; ++m)                                                  \
            _Pragma("unroll")                                                        \
            for (int n = 0; n < 4; ++n)                                              \
                acc[m][n] = __builtin_amdgcn_mfma_f32_16x16x32_bf16(aL0[m], b0[n], acc[m][n], 0, 0, 0); \
        PH_CLOSE                                                                     \
        /* Q2: aH0 reads; stage B-k1(t+1); vmcnt gate for k1(t) */                   \
        short8 aH0[4];                                                               \
        _Pragma("unroll")                                                            \
        for (int m = 0; m < 4; ++m) aH0[m] = *(const short8*)(a0p + ((m + 4) << 9)); \
        STAGE_B(t + 1, 1);                                                           \
        PH_OPEN                                                                      \
        _Pragma("unroll")                                                            \
        for (int m = 0; m < 4; ++m)                                                  \
            _Pragma("unroll")                                                        \
            for (int n = 0; n < 4; ++n)                                              \
                acc[m + 4][n] = __builtin_amdgcn_mfma_f32_16x16x32_bf16(aH0[m], b0[n], acc[m + 4][n], 0, 0, 0); \
        if (t < NT - 1) { PH_CLOSE_VM(8) } else { PH_CLOSE_VM(0) }                   \
        /* Q3: b1 + aL1 reads; stage A-k0(t+2) */                                    \
        short8 b1[4], aL1[4];                                                        \
        _Pragma("unroll")                                                            \
        for (int n = 0; n < 4; ++n) b1[n] = *(const short8*)(b1p + (n << 9));        \
        _Pragma("unroll")                                                            \
        for (int m = 0; m < 4; ++m) aL1[m] = *(const short8*)(a1p + (m << 9));       \
        STAGE_A(t + 2, 0);                                                           \
        PH_OPEN                                                                      \
        _Pragma("unroll")                                                            \
        for (int m = 0; m < 4; ++m)                                                  \
            _Pragma("unroll")                                                        \
            for (int n = 0; n < 4; ++n)                                              \
                acc[m][n] = __builtin_amdgcn_mfma_f32_16x16x32_bf16(aL1[m], b1[n], acc[m][n], 0, 0, 0); \
        PH_CLOSE                                                                     \
        /* Q4: aH1 reads; stage B-k0(t+2); vmcnt gate for k0(t+1) */                 \
        short8 aH1[4];                                                               \
        _Pragma("unroll")                                                            \
        for (int m = 0; m < 4; ++m) aH1[m] = *(const short8*)(a1p + ((m + 4) << 9)); \
        STAGE_B(t + 2, 0);                                                           \
        PH_OPEN                                                                      \
        _Pragma("unroll")                                                            \
        for (int m = 0; m < 4; ++m)                                                  \
            _Pragma("unroll")                                                        \
            for (int n = 0; n < 4; ++n)                                              \
                acc[m + 4][n] = __builtin_amdgcn_mfma_f32_16x16x32_bf16(aH1[m], b1[n], acc[m + 4][n], 0, 0, 0); \
        if (t < NT - 2) { PH_CLOSE_VM(8) } else { PH_CLOSE_VM(4) }                   \
    }

// ---- fused gate+up: H[M][HID] bf16 = silu(X@Wg^T)*(X@Wu^T), W' interleaved ----
__global__ __launch_bounds__(512, 1) void gemm_gateup(
    const unsigned short* __restrict__ X,
    const unsigned short* __restrict__ Wp,
    unsigned short* __restrict__ H)
{
    __shared__ __attribute__((aligned(16))) unsigned short As[2 * 2 * 8192];
    __shared__ __attribute__((aligned(16))) unsigned short Bs[2 * 2 * 8192];
    const int NT = DIM / 64;  // 32
    GEMM_PROLOGUE_COMMON(X, Wp, DIM, DIM)
    GEMM_KLOOP_BODY

    // epilogue: n even = gate frag, n odd = up frag (same H columns)
    const int lg = lane >> 4;
    #pragma unroll
    for (int m = 0; m < 8; ++m) {
        #pragma unroll
        for (int i = 0; i < 2; ++i) {
            f32x4 g = acc[m][2 * i], u = acc[m][2 * i + 1];
            const int col = (blockIdx.y << 7) + wc * 32 + i * 16 + lr;
            #pragma unroll
            for (int e = 0; e < 4; ++e) {
                const int row = m0 + wr * 128 + m * 16 + lg * 4 + e;
                float gv = g[e];
                float sg = gv / (1.0f + __expf(-gv));
                H[(size_t)row * HID + col] = f32_to_bf16_rne(sg * u[e]);
            }
        }
    }
}

// ---- down: Out[M][DIM] f32 = H @ Wd^T ----
__global__ __launch_bounds__(512, 1) void gemm_down(
    const unsigned short* __restrict__ Hb,
    const unsigned short* __restrict__ Wd,
    float* __restrict__ Out)
{
    __shared__ __attribute__((aligned(16))) unsigned short As[2 * 2 * 8192];
    __shared__ __attribute__((aligned(16))) unsigned short Bs[2 * 2 * 8192];
    const int NT = HID / 64;  // 88
    GEMM_PROLOGUE_COMMON(Hb, Wd, HID, HID)
    GEMM_KLOOP_BODY

    const int lg = lane >> 4;
    #pragma unroll
    for (int m = 0; m < 8; ++m) {
        #pragma unroll
        for (int n = 0; n < 4; ++n) {
            const int col = n0 + wc * 64 + n * 16 + lr;
            #pragma unroll
            for (int e = 0; e < 4; ++e) {
                const int row = m0 + wr * 128 + m * 16 + lg * 4 + e;
                Out[(size_t)row * DIM + col] = acc[m][n][e];
            }
        }
    }
}

extern "C" void kernel_launch(void* const* d_in, const int* in_sizes, int n_in,
                              void* d_out, int out_size, void* d_ws, size_t ws_size,
                              hipStream_t stream) {
    const float* x      = (const float*)d_in[0];
    const int* wq_gate  = (const int*)d_in[1];
    const float* s_gate = (const float*)d_in[2];
    const int* wq_up    = (const int*)d_in[3];
    const float* s_up   = (const float*)d_in[4];
    const int* wq_down  = (const int*)d_in[5];
    const float* s_down = (const float*)d_in[6];
    float* out = (float*)d_out;

    const int M = in_sizes[0] / DIM;  // 8192

    // ws layout (elems, bf16): xb [M*DIM] | wgu [2*HID*DIM] (down weights alias) | h [M*HID]
    unsigned short* xb  = (unsigned short*)d_ws;
    unsigned short* wgu = xb + (size_t)M * DIM;
    unsigned short* h   = wgu + (size_t)2 * HID * DIM;

    cast_f32_bf16<<<2048, 256, 0, stream>>>(x, xb, (long)M * DIM);
    dequant_gateup<<<2048, 256, 0, stream>>>(wq_gate, s_gate, wq_up, s_up, wgu);

    gemm_gateup<<<dim3(M / 256, (2 * HID) / 256), 512, 0, stream>>>(xb, wgu, h);

    dequant_plain<<<2048, 256, 0, stream>>>(wq_down, s_down, wgu, (long)DIM * HID, HID);

    gemm_down<<<dim3(M / 256, DIM / 256), 512, 0, stream>>>(h, wgu, out);
}